// Round 4
// baseline (452.505 us; speedup 1.0000x reference)
//
#include <hip/hip_runtime.h>
#include <hip/hip_bf16.h>

// Problem constants
#define BATCH   4096
#define HIDDEN  128
#define SESS    50
#define KTOT    4096
#define NSPLIT  4
#define KS      (KTOT / NSPLIT)     // 1024 per split
#define NB      ((size_t)BATCH * HIDDEN)   // 524288 elems per (B,H) buffer

typedef float f32x4 __attribute__((ext_vector_type(4)));

// ---------------------------------------------------------------------------
// K1: E[b][h] = sum_s emb[items[b][s]][h]   (all fp32)
// One block per batch row, 128 threads = one hidden element each.
// items dtype auto-detect (int64 would have zero odd words; P(misfire)~1e-40).
// ---------------------------------------------------------------------------
__global__ __launch_bounds__(128)
void gather_sum_kernel(const float* __restrict__ emb,
                       const int* __restrict__ items32,
                       float* __restrict__ E) {
    __shared__ int sidx[SESS];
    const int b = blockIdx.x;
    const int h = threadIdx.x;
    const bool is64 = (items32[1] | items32[3] | items32[5] | items32[7] |
                       items32[9] | items32[11] | items32[13] | items32[15]) == 0;
    if (h < SESS) {
        sidx[h] = is64 ? (int)((const long long*)items32)[(long)b * SESS + h]
                       : items32[b * SESS + h];
    }
    __syncthreads();
    float acc = 0.f;
#pragma unroll 5
    for (int s = 0; s < SESS; ++s) {
        acc += emb[(long)sidx[s] * HIDDEN + h];
    }
    E[(long)b * HIDDEN + h] = acc;
}

// ---------------------------------------------------------------------------
// K2/K4: Outp[s] = X[:, ks:ks+KS] @ B[ks:ks+KS, :]     (pure fp32 VALU)
// X: (4096 x 4096) row-major fp32. B: (4096 x 128) row-major fp32.
// grid = (128, NSPLIT); block = 256. Block computes 32 rows x 128 cols.
// Thread: cg = tid&31 -> cols 4cg..4cg+3 ; rg = tid>>5 -> rows 4rg..4rg+3.
// X rows loaded direct from global (32 lanes same addr -> broadcast);
// B rows streamed through L1/L2 (2 MB, cache-resident). No LDS, no MFMA,
// no bf16 -- this round isolates the MFMA-layout hypothesis.
// ---------------------------------------------------------------------------
__global__ __launch_bounds__(256)
void gemm_fp32_kernel(const float* __restrict__ X,
                      const float* __restrict__ B,
                      float* __restrict__ Outp) {
    const int tid = threadIdx.x;
    const int cg4 = (tid & 31) * 4;          // col base
    const int rg  = tid >> 5;                // 0..7
    const int r0  = blockIdx.x * 32 + rg * 4;
    const int ks  = blockIdx.y * KS;
    float* outp = Outp + (size_t)blockIdx.y * NB;

    f32x4 acc[4];
#pragma unroll
    for (int j = 0; j < 4; ++j) acc[j] = (f32x4){0.f, 0.f, 0.f, 0.f};

    const float* Bp = B + (long)ks * HIDDEN + cg4;
    const float* Xp = X + (long)r0 * KTOT + ks;

    for (int k = 0; k < KS; k += 4) {
        const f32x4 b0 = *(const f32x4*)(Bp + (long)(k + 0) * HIDDEN);
        const f32x4 b1 = *(const f32x4*)(Bp + (long)(k + 1) * HIDDEN);
        const f32x4 b2 = *(const f32x4*)(Bp + (long)(k + 2) * HIDDEN);
        const f32x4 b3 = *(const f32x4*)(Bp + (long)(k + 3) * HIDDEN);
#pragma unroll
        for (int j = 0; j < 4; ++j) {
            const f32x4 x = *(const f32x4*)(Xp + (long)j * KTOT + k);
            acc[j] += x[0] * b0;
            acc[j] += x[1] * b1;
            acc[j] += x[2] * b2;
            acc[j] += x[3] * b3;
        }
    }

#pragma unroll
    for (int j = 0; j < 4; ++j)
        *(f32x4*)(outp + (long)(r0 + j) * HIDDEN + cg4) = acc[j];
}

// ---------------------------------------------------------------------------
// K3: T = sum of NSPLIT partial buffers (elementwise, f32x4)
// grid = 512, block = 256: 512*256*4 = 524288 elems exactly.
// ---------------------------------------------------------------------------
__global__ __launch_bounds__(256)
void reduce4_kernel(const float* __restrict__ P, float* __restrict__ T) {
    const size_t i = ((size_t)blockIdx.x * 256 + threadIdx.x) * 4;
    f32x4 a = *(const f32x4*)(P + i);
    a += *(const f32x4*)(P + NB + i);
    a += *(const f32x4*)(P + 2 * NB + i);
    a += *(const f32x4*)(P + 3 * NB + i);
    *(f32x4*)(T + i) = a;
}

// ---------------------------------------------------------------------------
// K5: out[row] = normalize( sum of NSPLIT partial R buffers )  (row L2 norm)
// One block per row, 128 threads.
// ---------------------------------------------------------------------------
__global__ __launch_bounds__(128)
void reduce_norm_kernel(const float* __restrict__ P, float* __restrict__ out) {
    __shared__ float s[128];
    const int row = blockIdx.x;
    const int h   = threadIdx.x;
    const size_t i = (size_t)row * HIDDEN + h;
    float v = P[i] + P[NB + i] + P[2 * NB + i] + P[3 * NB + i];
    s[h] = v * v;
    __syncthreads();
#pragma unroll
    for (int o = 64; o > 0; o >>= 1) {
        if (h < o) s[h] += s[h + o];
        __syncthreads();
    }
    out[i] = v * rsqrtf(s[0]);
}

// ---------------------------------------------------------------------------
// out = normalize_rows( D @ (A @ E) )   [associativity: 137 GF -> 8.6 GF]
// All fp32 this round (bug isolation: no MFMA, no bf16).
// ws layout (floats): E[NB] | Tp[4*NB] | T[NB] | Rp[4*NB]  = 20 MB
// ---------------------------------------------------------------------------
extern "C" void kernel_launch(void* const* d_in, const int* in_sizes, int n_in,
                              void* d_out, int out_size, void* d_ws, size_t ws_size,
                              hipStream_t stream) {
    const float* emb   = (const float*)d_in[0];
    const int*   items = (const int*)d_in[1];
    const float* A     = (const float*)d_in[2];
    const float* D     = (const float*)d_in[3];
    // d_in[4] (target_embedding) is unused by the reference.
    float* out = (float*)d_out;

    float* E  = (float*)d_ws;
    float* Tp = E + NB;
    float* T  = Tp + 4 * NB;
    float* Rp = T + NB;

    gather_sum_kernel<<<BATCH, HIDDEN, 0, stream>>>(emb, items, E);

    gemm_fp32_kernel<<<dim3(BATCH / 32, NSPLIT), 256, 0, stream>>>(A, E, Tp);
    reduce4_kernel<<<512, 256, 0, stream>>>(Tp, T);

    gemm_fp32_kernel<<<dim3(BATCH / 32, NSPLIT), 256, 0, stream>>>(D, T, Rp);
    reduce_norm_kernel<<<BATCH, HIDDEN, 0, stream>>>(Rp, out);
}

// Round 5
// 269.603 us; speedup vs baseline: 1.6784x; 1.6784x over previous
//
#include <hip/hip_runtime.h>
#include <hip/hip_bf16.h>

// Problem constants
#define BATCH   4096
#define HIDDEN  128
#define SESS    50
#define KTOT    4096
#define NB      ((size_t)BATCH * HIDDEN)   // 524288 elems per (B,H) buffer

typedef __bf16 bf16x8 __attribute__((ext_vector_type(8)));
typedef float  f32x4  __attribute__((ext_vector_type(4)));
typedef unsigned char uchar;

__device__ __forceinline__ f32x4 mfma_bf16(bf16x8 a, bf16x8 b, f32x4 c) {
    return __builtin_amdgcn_mfma_f32_16x16x32_bf16(a, b, c, 0, 0, 0);
}

// ---------------------------------------------------------------------------
// PROBE: determine the 16x16x32 bf16 MFMA C/D layout empirically and verify
// the full A/B/C-D convention end-to-end against an exact integer reference.
// Writes: flag (1 = MFMA path validated), row_tab[256], col_tab[256]
// (uchar, indexed lane*4+reg -> row/col of D within the 16x16 tile).
// One-hot k=0 probes are valid under any sane k-map with (quad0,j0)->k0;
// the exact-match check on probe 3 certifies the k-pairing used by the
// main GEMM (both frags loaded k-contiguous-8 per quad).
// ---------------------------------------------------------------------------
__global__ __launch_bounds__(64)
void probe_kernel(int* __restrict__ flag, uchar* __restrict__ rtab,
                  uchar* __restrict__ ctab) {
    __shared__ float As[16][32];
    __shared__ float Bs[32][16];
    __shared__ int cnt[256];
    const int lane = threadIdx.x;
    for (int idx = lane; idx < 512; idx += 64) {
        const int m = idx >> 5, k = idx & 31;
        As[m][k] = (float)(((m * 5 + k * 3) % 17) - 8);
        const int kb = idx >> 4, n = idx & 15;
        Bs[kb][n] = (float)(((kb * 7 + n * 11) % 17) - 8);
    }
    for (int i = lane; i < 256; i += 64) cnt[i] = 0;
    __syncthreads();

    const int lo = lane & 15, quad = lane >> 4;
    bf16x8 a, b, a1, b1, a2, b2;
#pragma unroll
    for (int j = 0; j < 8; ++j) {
        a[j]  = (__bf16)As[lo][quad * 8 + j];
        b[j]  = (__bf16)Bs[quad * 8 + j][lo];
        a1[j] = (__bf16)0.f; b1[j] = (__bf16)0.f;
        a2[j] = (__bf16)0.f; b2[j] = (__bf16)0.f;
    }
    if (quad == 0) {
        a1[0] = (__bf16)(float)lo;  b1[0] = (__bf16)1.f;   // D1[m][n] = m
        a2[0] = (__bf16)1.f;        b2[0] = (__bf16)(float)lo; // D2[m][n] = n
    }
    const f32x4 z = {0.f, 0.f, 0.f, 0.f};
    f32x4 d  = mfma_bf16(a,  b,  z);
    f32x4 d1 = mfma_bf16(a1, b1, z);
    f32x4 d2 = mfma_bf16(a2, b2, z);

    bool ok = true;
    int ms[4], ns[4];
#pragma unroll
    for (int r = 0; r < 4; ++r) {
        const int m = (int)d1[r], n = (int)d2[r];
        ok = ok && ((float)m == d1[r]) && ((float)n == d2[r]) &&
             (m >= 0) && (m < 16) && (n >= 0) && (n < 16);
        ms[r] = m & 15; ns[r] = n & 15;
        float ref = 0.f;
        for (int k = 0; k < 32; ++k) ref += As[ms[r]][k] * Bs[k][ns[r]];
        ok = ok && (d[r] == ref);   // exact: all values integer, < 2^24
        atomicAdd(&cnt[ms[r] * 16 + ns[r]], 1);
    }
    __syncthreads();
    bool comp = true;
    for (int i = lane; i < 256; i += 64) comp = comp && (cnt[i] == 1);

    const unsigned long long b_ok   = __ballot(ok);
    const unsigned long long b_comp = __ballot(comp);
#pragma unroll
    for (int r = 0; r < 4; ++r) {
        rtab[lane * 4 + r] = (uchar)ms[r];
        ctab[lane * 4 + r] = (uchar)ns[r];
    }
    if (lane == 0)
        *flag = (b_ok == ~0ULL && b_comp == ~0ULL) ? 1 : 0;
}

// ---------------------------------------------------------------------------
// Gather: E[b][h] = sum_s emb[items[b][s]][h]  -> Ef (fp32, row-major)
//                                              -> ET (bf16, transposed 128x4096)
// 4 batch rows per block; thread = (row r = t>>5, 16B chunk c4 = (t&31)*4).
// items dtype auto-detect (int64 would have all-zero odd words).
// ---------------------------------------------------------------------------
__global__ __launch_bounds__(128)
void gather_sum_kernel(const float* __restrict__ emb,
                       const int* __restrict__ items32,
                       float* __restrict__ Ef,
                       __bf16* __restrict__ ET) {
    __shared__ int sidx[4][SESS];
    const int t = threadIdx.x;
    const int b0 = blockIdx.x * 4;
    const bool is64 = (items32[1] | items32[3] | items32[5] | items32[7] |
                       items32[9] | items32[11] | items32[13] | items32[15]) == 0;
    for (int i = t; i < 4 * SESS; i += 128) {
        sidx[i / SESS][i % SESS] =
            is64 ? (int)((const long long*)items32)[(long)b0 * SESS + i]
                 : items32[b0 * SESS + i];
    }
    __syncthreads();
    const int r  = t >> 5;
    const int c4 = (t & 31) * 4;
    const int b  = b0 + r;
    f32x4 acc = {0.f, 0.f, 0.f, 0.f};
#pragma unroll 5
    for (int s = 0; s < SESS; ++s) {
        acc += *(const f32x4*)(emb + (long)sidx[r][s] * HIDDEN + c4);
    }
    *(f32x4*)(Ef + (long)b * HIDDEN + c4) = acc;
#pragma unroll
    for (int j = 0; j < 4; ++j)
        ET[(long)(c4 + j) * BATCH + b] = (__bf16)acc[j];
}

// ---------------------------------------------------------------------------
// MFMA GEMM (runs iff *flag == 1): partial_s = X[:, s*1024:(s+1)*1024] @ B
// X fp32 row-major (converted to bf16 in-flight); B given transposed bf16
// (BT: 128 x 4096) so B-fragments are contiguous 16B loads.
// grid (256, 4): blockIdx.x = 16-row group, blockIdx.y = k-superslice s.
// 4 waves further split k (256 each); LDS cross-wave reduce; fp32 partial out.
// Epilogue uses the PROBED C/D tables -> correct under any hardware layout.
// PHASE 1: partials -> Tp + s*NB.  PHASE 2: partials -> Tp+(s+1)*NB / RpX.
// ---------------------------------------------------------------------------
template <int PHASE>
__global__ __launch_bounds__(256)
void gemm_mfma_kernel(const float* __restrict__ X,
                      const __bf16* __restrict__ BT,
                      const int* __restrict__ flag,
                      const uchar* __restrict__ rtab,
                      const uchar* __restrict__ ctab,
                      float* __restrict__ Tp,
                      float* __restrict__ RpX) {
    if (*flag != 1) return;
    __shared__ float red[4][16][128];   // 32 KB

    const int tid  = threadIdx.x;
    const int wave = tid >> 6;
    const int lane = tid & 63;
    const int lo   = lane & 15;
    const int quad = lane >> 4;
    const int rowBase = blockIdx.x * 16;
    const int sy      = blockIdx.y;
    const int kBase   = sy * 1024 + wave * 256;

    const unsigned rt4 = ((const unsigned*)rtab)[lane];
    const unsigned ct4 = ((const unsigned*)ctab)[lane];

    f32x4 acc[8];
#pragma unroll
    for (int i = 0; i < 8; ++i) acc[i] = (f32x4){0.f, 0.f, 0.f, 0.f};

    const long aOff = (long)(rowBase + lo) * KTOT;
#pragma unroll 2
    for (int kk = 0; kk < 256; kk += 32) {
        const int k0 = kBase + kk + quad * 8;
        const float* ap = X + aOff + k0;
        const f32x4 x0 = *(const f32x4*)(ap);
        const f32x4 x1 = *(const f32x4*)(ap + 4);
        bf16x8 a;
        a[0] = (__bf16)x0[0]; a[1] = (__bf16)x0[1];
        a[2] = (__bf16)x0[2]; a[3] = (__bf16)x0[3];
        a[4] = (__bf16)x1[0]; a[5] = (__bf16)x1[1];
        a[6] = (__bf16)x1[2]; a[7] = (__bf16)x1[3];
#pragma unroll
        for (int nt = 0; nt < 8; ++nt) {
            const bf16x8 bb = *(const bf16x8*)(BT + (long)(nt * 16 + lo) * KTOT + k0);
            acc[nt] = mfma_bf16(a, bb, acc[nt]);
        }
    }

    // scatter per-wave partials via probed C/D tables
#pragma unroll
    for (int r = 0; r < 4; ++r) {
        const int dr = (rt4 >> (8 * r)) & 255;
        const int dc = (ct4 >> (8 * r)) & 255;
#pragma unroll
        for (int nt = 0; nt < 8; ++nt)
            red[wave][dr][nt * 16 + dc] = acc[nt][r];
    }
    __syncthreads();

    float* outp = (PHASE == 1) ? (Tp + (size_t)sy * NB)
                               : (sy < 3 ? Tp + (size_t)(sy + 1) * NB : RpX);
    // cross-wave reduce; thread -> (row = tid>>4, 8 cols at cb=(tid&15)*8)
    const int row = tid >> 4;
    const int cb  = (tid & 15) * 8;
    f32x4 v0, v1;
#pragma unroll
    for (int j = 0; j < 4; ++j) {
        v0[j] = red[0][row][cb + j] + red[1][row][cb + j] +
                red[2][row][cb + j] + red[3][row][cb + j];
        v1[j] = red[0][row][cb + 4 + j] + red[1][row][cb + 4 + j] +
                red[2][row][cb + 4 + j] + red[3][row][cb + 4 + j];
    }
    *(f32x4*)(outp + (long)(rowBase + row) * HIDDEN + cb)     = v0;
    *(f32x4*)(outp + (long)(rowBase + row) * HIDDEN + cb + 4) = v1;
}

// ---------------------------------------------------------------------------
// fp32 VALU GEMM fallback (runs iff *flag != 1) — R4-proven structure.
// grid (128, 4); block computes 32 rows x 128 cols of a k-slice of 1024.
// ---------------------------------------------------------------------------
template <int PHASE>
__global__ __launch_bounds__(256)
void gemm_fp32_kernel(const float* __restrict__ X,
                      const float* __restrict__ B,
                      const int* __restrict__ flag,
                      float* __restrict__ Tp,
                      float* __restrict__ RpX) {
    if (*flag == 1) return;
    const int tid = threadIdx.x;
    const int cg4 = (tid & 31) * 4;
    const int rg  = tid >> 5;
    const int r0  = blockIdx.x * 32 + rg * 4;
    const int sy  = blockIdx.y;
    const int ks  = sy * 1024;
    float* outp = (PHASE == 1) ? (Tp + (size_t)sy * NB)
                               : (sy < 3 ? Tp + (size_t)(sy + 1) * NB : RpX);

    f32x4 acc[4];
#pragma unroll
    for (int j = 0; j < 4; ++j) acc[j] = (f32x4){0.f, 0.f, 0.f, 0.f};

    const float* Bp = B + (long)ks * HIDDEN + cg4;
    const float* Xp = X + (long)r0 * KTOT + ks;

    for (int k = 0; k < 1024; k += 4) {
        const f32x4 b0 = *(const f32x4*)(Bp + (long)(k + 0) * HIDDEN);
        const f32x4 b1 = *(const f32x4*)(Bp + (long)(k + 1) * HIDDEN);
        const f32x4 b2 = *(const f32x4*)(Bp + (long)(k + 2) * HIDDEN);
        const f32x4 b3 = *(const f32x4*)(Bp + (long)(k + 3) * HIDDEN);
#pragma unroll
        for (int j = 0; j < 4; ++j) {
            const f32x4 x = *(const f32x4*)(Xp + (long)j * KTOT + k);
            acc[j] += x[0] * b0;
            acc[j] += x[1] * b1;
            acc[j] += x[2] * b2;
            acc[j] += x[3] * b3;
        }
    }
#pragma unroll
    for (int j = 0; j < 4; ++j)
        *(f32x4*)(outp + (long)(r0 + j) * HIDDEN + cg4) = acc[j];
}

// ---------------------------------------------------------------------------
// reduce4: T = sum of 4 partials (into Tp[0], in-place safe: elementwise)
// and TT (bf16 transpose of T) for the MFMA phase-2 B-operand.
// grid 512 x 256: 512*256*4 = NB elems.
// ---------------------------------------------------------------------------
__global__ __launch_bounds__(256)
void reduce4_kernel(float* __restrict__ Tp, __bf16* __restrict__ TT) {
    const size_t i = ((size_t)blockIdx.x * 256 + threadIdx.x) * 4;
    f32x4 a = *(const f32x4*)(Tp + i);
    a += *(const f32x4*)(Tp + NB + i);
    a += *(const f32x4*)(Tp + 2 * NB + i);
    a += *(const f32x4*)(Tp + 3 * NB + i);
    *(f32x4*)(Tp + i) = a;
    const int b = (int)(i >> 7);
    const int h = (int)(i & 127);
#pragma unroll
    for (int j = 0; j < 4; ++j)
        TT[(long)(h + j) * BATCH + b] = (__bf16)a[j];
}

// ---------------------------------------------------------------------------
// reduce_norm: out[row] = normalize( sum of 4 phase-2 partials )
// Partial slots: Tp[1..3] and RpX.  One block per row, 128 threads.
// ---------------------------------------------------------------------------
__global__ __launch_bounds__(128)
void reduce_norm_kernel(const float* __restrict__ Tp,
                        const float* __restrict__ RpX,
                        float* __restrict__ out) {
    __shared__ float s[128];
    const int row = blockIdx.x;
    const int h   = threadIdx.x;
    const size_t i = (size_t)row * HIDDEN + h;
    const float v = Tp[NB + i] + Tp[2 * NB + i] + Tp[3 * NB + i] + RpX[i];
    s[h] = v * v;
    __syncthreads();
#pragma unroll
    for (int o = 64; o > 0; o >>= 1) {
        if (h < o) s[h] += s[h + o];
        __syncthreads();
    }
    out[i] = v * rsqrtf(s[0]);
}

// ---------------------------------------------------------------------------
// out = normalize_rows( D @ (A @ E) )   [associativity: 137 GF -> 8.6 GF]
// Self-probing MFMA fast path with fp32 VALU fallback (flag-gated).
// ws (bytes): [0:4) flag | [64:320) rtab | [320:576) ctab | 1 KB header,
// then Ef fp32 (2MB) | ET bf16 (1MB) | TT bf16 (1MB) | Tp fp32 x4 (8MB)
// | RpX fp32 (2MB)  -> ~14 MB total.
// ---------------------------------------------------------------------------
extern "C" void kernel_launch(void* const* d_in, const int* in_sizes, int n_in,
                              void* d_out, int out_size, void* d_ws, size_t ws_size,
                              hipStream_t stream) {
    const float* emb   = (const float*)d_in[0];
    const int*   items = (const int*)d_in[1];
    const float* A     = (const float*)d_in[2];
    const float* D     = (const float*)d_in[3];
    // d_in[4] (target_embedding) is unused by the reference.
    float* out = (float*)d_out;

    uchar* base = (uchar*)d_ws;
    int*   flag = (int*)base;
    uchar* rtab = base + 64;
    uchar* ctab = base + 320;
    float*  Ef  = (float*)(base + 1024);
    __bf16* ET  = (__bf16*)(Ef + NB);
    __bf16* TT  = ET + NB;
    float*  Tp  = (float*)(TT + NB);
    float*  RpX = Tp + 4 * NB;

    probe_kernel<<<1, 64, 0, stream>>>(flag, rtab, ctab);
    gather_sum_kernel<<<BATCH / 4, 128, 0, stream>>>(emb, items, Ef, ET);

    // Phase 1: T = A @ E
    gemm_mfma_kernel<1><<<dim3(BATCH / 16, 4), 256, 0, stream>>>(A, ET, flag, rtab, ctab, Tp, RpX);
    gemm_fp32_kernel<1><<<dim3(BATCH / 32, 4), 256, 0, stream>>>(A, Ef, flag, Tp, RpX);
    reduce4_kernel<<<512, 256, 0, stream>>>(Tp, TT);

    // Phase 2: R = D @ T, then row-normalize
    gemm_mfma_kernel<2><<<dim3(BATCH / 16, 4), 256, 0, stream>>>(D, TT, flag, rtab, ctab, Tp, RpX);
    gemm_fp32_kernel<2><<<dim3(BATCH / 32, 4), 256, 0, stream>>>(D, Tp, flag, Tp, RpX);
    reduce_norm_kernel<<<BATCH, 128, 0, stream>>>(Tp, RpX, out);
}

// Round 6
// 238.677 us; speedup vs baseline: 1.8959x; 1.1296x over previous
//
#include <hip/hip_runtime.h>
#include <hip/hip_bf16.h>

// Problem constants
#define BATCH   4096
#define HIDDEN  128
#define SESS    50
#define KTOT    4096
#define NB      ((size_t)BATCH * HIDDEN)   // 524288 elems per (B,H) buffer

typedef __bf16 bf16x8 __attribute__((ext_vector_type(8)));
typedef float  f32x4  __attribute__((ext_vector_type(4)));
typedef unsigned char uchar;

__device__ __forceinline__ f32x4 mfma_bf16(bf16x8 a, bf16x8 b, f32x4 c) {
    return __builtin_amdgcn_mfma_f32_16x16x32_bf16(a, b, c, 0, 0, 0);
}

// Packed B-operand layout: elem(k, h) -> (k>>3)*1024 + (h>>4)*128 + (h&15)*8 + (k&7)
// GEMM reads: lane (lo,quad), k-step base ks=(k0>>3): addr = (ks+quad)*1024 + lo*8,
// n-tile nt at +nt*128 elems (256B imm), k-step advance = +4096 elems (8KB).
// Each wave streams contiguous 8KB per 32-k step -> perfectly coalesced.
__device__ __forceinline__ long packBH(int k, int h) {
    return ((long)(k >> 3) << 10) + ((h >> 4) << 7) + ((h & 15) << 3) + (k & 7);
}

// ---------------------------------------------------------------------------
// PROBE (R5-validated): decode 16x16x32 bf16 MFMA C/D layout + exact check.
// flag=1 => MFMA path safe; tables rtab/ctab give (lane,reg)->(row,col).
// ---------------------------------------------------------------------------
__global__ __launch_bounds__(64)
void probe_kernel(int* __restrict__ flag, uchar* __restrict__ rtab,
                  uchar* __restrict__ ctab) {
    __shared__ float As[16][32];
    __shared__ float Bs[32][16];
    __shared__ int cnt[256];
    const int lane = threadIdx.x;
    for (int idx = lane; idx < 512; idx += 64) {
        const int m = idx >> 5, k = idx & 31;
        As[m][k] = (float)(((m * 5 + k * 3) % 17) - 8);
        const int kb = idx >> 4, n = idx & 15;
        Bs[kb][n] = (float)(((kb * 7 + n * 11) % 17) - 8);
    }
    for (int i = lane; i < 256; i += 64) cnt[i] = 0;
    __syncthreads();

    const int lo = lane & 15, quad = lane >> 4;
    bf16x8 a, b, a1, b1, a2, b2;
#pragma unroll
    for (int j = 0; j < 8; ++j) {
        a[j]  = (__bf16)As[lo][quad * 8 + j];
        b[j]  = (__bf16)Bs[quad * 8 + j][lo];
        a1[j] = (__bf16)0.f; b1[j] = (__bf16)0.f;
        a2[j] = (__bf16)0.f; b2[j] = (__bf16)0.f;
    }
    if (quad == 0) {
        a1[0] = (__bf16)(float)lo;  b1[0] = (__bf16)1.f;      // D1[m][n] = m
        a2[0] = (__bf16)1.f;        b2[0] = (__bf16)(float)lo; // D2[m][n] = n
    }
    const f32x4 z = {0.f, 0.f, 0.f, 0.f};
    f32x4 d  = mfma_bf16(a,  b,  z);
    f32x4 d1 = mfma_bf16(a1, b1, z);
    f32x4 d2 = mfma_bf16(a2, b2, z);

    bool ok = true;
    int ms[4], ns[4];
#pragma unroll
    for (int r = 0; r < 4; ++r) {
        const int m = (int)d1[r], n = (int)d2[r];
        ok = ok && ((float)m == d1[r]) && ((float)n == d2[r]) &&
             (m >= 0) && (m < 16) && (n >= 0) && (n < 16);
        ms[r] = m & 15; ns[r] = n & 15;
        float ref = 0.f;
        for (int k = 0; k < 32; ++k) ref += As[ms[r]][k] * Bs[k][ns[r]];
        ok = ok && (d[r] == ref);   // exact: integer values < 2^24
        atomicAdd(&cnt[ms[r] * 16 + ns[r]], 1);
    }
    __syncthreads();
    bool comp = true;
    for (int i = lane; i < 256; i += 64) comp = comp && (cnt[i] == 1);

    const unsigned long long b_ok   = __ballot(ok);
    const unsigned long long b_comp = __ballot(comp);
#pragma unroll
    for (int r = 0; r < 4; ++r) {
        rtab[lane * 4 + r] = (uchar)ms[r];
        ctab[lane * 4 + r] = (uchar)ns[r];
    }
    if (lane == 0)
        *flag = (b_ok == ~0ULL && b_comp == ~0ULL) ? 1 : 0;
}

// ---------------------------------------------------------------------------
// Gather v2: E[b][h] = sum_s emb[items[b][s]][h]
//   -> Ef  (fp32 row-major, for fp32 fallback path)
//   -> ETp (bf16, packed MFMA-B layout)
// grid 2048 x 256 thr (8 blocks/CU, 32 waves/CU). Thread = (row r=t>>7,
// s-group g=(t>>5)&3, chunk c=t&31); ~13 independent f32x4 loads in flight.
// ---------------------------------------------------------------------------
__global__ __launch_bounds__(256)
void gather_sum_kernel(const float* __restrict__ emb,
                       const int* __restrict__ items32,
                       float* __restrict__ Ef,
                       __bf16* __restrict__ ETp) {
    __shared__ int sidx[2][SESS];
    __shared__ f32x4 red[2][4][32];   // 4 KB
    const int t  = threadIdx.x;
    const int b0 = blockIdx.x * 2;
    const bool is64 = (items32[1] | items32[3] | items32[5] | items32[7] |
                       items32[9] | items32[11] | items32[13] | items32[15]) == 0;
    if (t < 2 * SESS) {
        sidx[t / SESS][t % SESS] =
            is64 ? (int)((const long long*)items32)[(long)b0 * SESS + t]
                 : items32[b0 * SESS + t];
    }
    __syncthreads();
    const int r  = t >> 7;
    const int g  = (t >> 5) & 3;
    const int c4 = (t & 31) * 4;
    f32x4 acc = {0.f, 0.f, 0.f, 0.f};
#pragma unroll
    for (int s = g; s < SESS; s += 4) {
        acc += *(const f32x4*)(emb + (long)sidx[r][s] * HIDDEN + c4);
    }
    red[r][g][t & 31] = acc;
    __syncthreads();
    if (g == 0) {
        const int b = b0 + r;
        const f32x4 v = red[r][0][t & 31] + red[r][1][t & 31] +
                        red[r][2][t & 31] + red[r][3][t & 31];
        *(f32x4*)(Ef + (long)b * HIDDEN + c4) = v;
        const long pb = ((long)(b >> 3) << 10) + (b & 7) + ((c4 >> 4) << 7);
#pragma unroll
        for (int j = 0; j < 4; ++j)
            ETp[pb + ((c4 & 15) + j) * 8] = (__bf16)v[j];
    }
}

// ---------------------------------------------------------------------------
// MFMA GEMM v2 (runs iff *flag==1): partial_s = X[:, s*1024:(s+1)*1024] @ B
// X fp32 row-major (bf16-converted in flight); B in packed layout (BTp).
// grid (256,4); 4 waves split the 1024-k superslice (256 each).
// Register double-buffered K-loop: next iter's 2 X-loads + 8 B-frags issued
// before current iter's MFMAs -> ~10 loads in flight per wave, always.
// Epilogue scatters via PROBED C/D tables, LDS cross-wave reduce, fp32 out.
// ---------------------------------------------------------------------------
template <int PHASE>
__global__ __launch_bounds__(256, 4)
void gemm_mfma_kernel(const float* __restrict__ X,
                      const __bf16* __restrict__ BTp,
                      const int* __restrict__ flag,
                      const uchar* __restrict__ rtab,
                      const uchar* __restrict__ ctab,
                      float* __restrict__ Tp,
                      float* __restrict__ RpX) {
    if (*flag != 1) return;
    __shared__ float red[4][16][128];   // 32 KB

    const int tid  = threadIdx.x;
    const int wave = tid >> 6;
    const int lane = tid & 63;
    const int lo   = lane & 15;
    const int quad = lane >> 4;
    const int rowBase = blockIdx.x * 16;
    const int sy      = blockIdx.y;
    const int kBase   = sy * 1024 + wave * 256;

    const unsigned rt4 = ((const unsigned*)rtab)[lane];
    const unsigned ct4 = ((const unsigned*)ctab)[lane];

    f32x4 acc[8];
#pragma unroll
    for (int i = 0; i < 8; ++i) acc[i] = (f32x4){0.f, 0.f, 0.f, 0.f};

    const float*  ap = X + (long)(rowBase + lo) * KTOT + kBase + quad * 8;
    const __bf16* bp = BTp + (((long)(kBase >> 3) + quad) << 10) + lo * 8;

    // prologue: iter 0 loads
    f32x4 x0 = *(const f32x4*)(ap);
    f32x4 x1 = *(const f32x4*)(ap + 4);
    bf16x8 bb[8];
#pragma unroll
    for (int nt = 0; nt < 8; ++nt)
        bb[nt] = *(const bf16x8*)(bp + nt * 128);

#pragma unroll
    for (int it = 0; it < 7; ++it) {
        // prefetch iter it+1
        const float*  ap2 = ap + (it + 1) * 32;
        const __bf16* bp2 = bp + (long)(it + 1) * 4096;
        const f32x4 nx0 = *(const f32x4*)(ap2);
        const f32x4 nx1 = *(const f32x4*)(ap2 + 4);
        bf16x8 nb[8];
#pragma unroll
        for (int nt = 0; nt < 8; ++nt)
            nb[nt] = *(const bf16x8*)(bp2 + nt * 128);
        // compute iter it
        bf16x8 a;
        a[0] = (__bf16)x0[0]; a[1] = (__bf16)x0[1];
        a[2] = (__bf16)x0[2]; a[3] = (__bf16)x0[3];
        a[4] = (__bf16)x1[0]; a[5] = (__bf16)x1[1];
        a[6] = (__bf16)x1[2]; a[7] = (__bf16)x1[3];
#pragma unroll
        for (int nt = 0; nt < 8; ++nt)
            acc[nt] = mfma_bf16(a, bb[nt], acc[nt]);
        // rotate
        x0 = nx0; x1 = nx1;
#pragma unroll
        for (int nt = 0; nt < 8; ++nt) bb[nt] = nb[nt];
    }
    {   // last iter
        bf16x8 a;
        a[0] = (__bf16)x0[0]; a[1] = (__bf16)x0[1];
        a[2] = (__bf16)x0[2]; a[3] = (__bf16)x0[3];
        a[4] = (__bf16)x1[0]; a[5] = (__bf16)x1[1];
        a[6] = (__bf16)x1[2]; a[7] = (__bf16)x1[3];
#pragma unroll
        for (int nt = 0; nt < 8; ++nt)
            acc[nt] = mfma_bf16(a, bb[nt], acc[nt]);
    }

    // scatter per-wave partials via probed C/D tables
#pragma unroll
    for (int r = 0; r < 4; ++r) {
        const int dr = (rt4 >> (8 * r)) & 255;
        const int dc = (ct4 >> (8 * r)) & 255;
#pragma unroll
        for (int nt = 0; nt < 8; ++nt)
            red[wave][dr][nt * 16 + dc] = acc[nt][r];
    }
    __syncthreads();

    float* outp = (PHASE == 1) ? (Tp + (size_t)sy * NB)
                               : (sy < 3 ? Tp + (size_t)(sy + 1) * NB : RpX);
    const int row = tid >> 4;
    const int cb  = (tid & 15) * 8;
    f32x4 v0, v1;
#pragma unroll
    for (int j = 0; j < 4; ++j) {
        v0[j] = red[0][row][cb + j] + red[1][row][cb + j] +
                red[2][row][cb + j] + red[3][row][cb + j];
        v1[j] = red[0][row][cb + 4 + j] + red[1][row][cb + 4 + j] +
                red[2][row][cb + 4 + j] + red[3][row][cb + 4 + j];
    }
    *(f32x4*)(outp + (long)(rowBase + row) * HIDDEN + cb)     = v0;
    *(f32x4*)(outp + (long)(rowBase + row) * HIDDEN + cb + 4) = v1;
}

// ---------------------------------------------------------------------------
// fp32 VALU GEMM fallback (runs iff *flag != 1) — R4-proven structure.
// ---------------------------------------------------------------------------
template <int PHASE>
__global__ __launch_bounds__(256)
void gemm_fp32_kernel(const float* __restrict__ X,
                      const float* __restrict__ B,
                      const int* __restrict__ flag,
                      float* __restrict__ Tp,
                      float* __restrict__ RpX) {
    if (*flag == 1) return;
    const int tid = threadIdx.x;
    const int cg4 = (tid & 31) * 4;
    const int rg  = tid >> 5;
    const int r0  = blockIdx.x * 32 + rg * 4;
    const int sy  = blockIdx.y;
    const int ks  = sy * 1024;
    float* outp = (PHASE == 1) ? (Tp + (size_t)sy * NB)
                               : (sy < 3 ? Tp + (size_t)(sy + 1) * NB : RpX);

    f32x4 acc[4];
#pragma unroll
    for (int j = 0; j < 4; ++j) acc[j] = (f32x4){0.f, 0.f, 0.f, 0.f};

    const float* Bp = B + (long)ks * HIDDEN + cg4;
    const float* Xp = X + (long)r0 * KTOT + ks;

    for (int k = 0; k < 1024; k += 4) {
        const f32x4 b0 = *(const f32x4*)(Bp + (long)(k + 0) * HIDDEN);
        const f32x4 b1 = *(const f32x4*)(Bp + (long)(k + 1) * HIDDEN);
        const f32x4 b2 = *(const f32x4*)(Bp + (long)(k + 2) * HIDDEN);
        const f32x4 b3 = *(const f32x4*)(Bp + (long)(k + 3) * HIDDEN);
#pragma unroll
        for (int j = 0; j < 4; ++j) {
            const f32x4 x = *(const f32x4*)(Xp + (long)j * KTOT + k);
            acc[j] += x[0] * b0;
            acc[j] += x[1] * b1;
            acc[j] += x[2] * b2;
            acc[j] += x[3] * b3;
        }
    }
#pragma unroll
    for (int j = 0; j < 4; ++j)
        *(f32x4*)(outp + (long)(r0 + j) * HIDDEN + cg4) = acc[j];
}

// ---------------------------------------------------------------------------
// reduce4: T = sum of 4 partials -> Tp[0] (fp32, fallback B) and TTp (packed
// bf16, MFMA phase-2 B). grid 512 x 256.
// ---------------------------------------------------------------------------
__global__ __launch_bounds__(256)
void reduce4_kernel(float* __restrict__ Tp, __bf16* __restrict__ TTp) {
    const size_t i = ((size_t)blockIdx.x * 256 + threadIdx.x) * 4;
    f32x4 a = *(const f32x4*)(Tp + i);
    a += *(const f32x4*)(Tp + NB + i);
    a += *(const f32x4*)(Tp + 2 * NB + i);
    a += *(const f32x4*)(Tp + 3 * NB + i);
    *(f32x4*)(Tp + i) = a;
    const int b  = (int)(i >> 7);
    const int h0 = (int)(i & 127);
    const long pb = ((long)(b >> 3) << 10) + (b & 7) + ((h0 >> 4) << 7);
#pragma unroll
    for (int j = 0; j < 4; ++j)
        TTp[pb + ((h0 & 15) + j) * 8] = (__bf16)a[j];
}

// ---------------------------------------------------------------------------
// reduce_norm: out[row] = normalize( Tp[1] + Tp[2] + Tp[3] + RpX ).
// ---------------------------------------------------------------------------
__global__ __launch_bounds__(128)
void reduce_norm_kernel(const float* __restrict__ Tp,
                        const float* __restrict__ RpX,
                        float* __restrict__ out) {
    __shared__ float s[128];
    const int row = blockIdx.x;
    const int h   = threadIdx.x;
    const size_t i = (size_t)row * HIDDEN + h;
    const float v = Tp[NB + i] + Tp[2 * NB + i] + Tp[3 * NB + i] + RpX[i];
    s[h] = v * v;
    __syncthreads();
#pragma unroll
    for (int o = 64; o > 0; o >>= 1) {
        if (h < o) s[h] += s[h + o];
        __syncthreads();
    }
    out[i] = v * rsqrtf(s[0]);
}

// ---------------------------------------------------------------------------
// out = normalize_rows( D @ (A @ E) )   [associativity: 137 GF -> 8.6 GF]
// Self-probing MFMA fast path (packed-B, double-buffered) + fp32 fallback.
// ws: 1KB header | Ef fp32 2MB | ETp bf16 1MB | TTp bf16 1MB | Tp fp32 x4 8MB
//     | RpX fp32 2MB  (~14 MB, same as R5)
// ---------------------------------------------------------------------------
extern "C" void kernel_launch(void* const* d_in, const int* in_sizes, int n_in,
                              void* d_out, int out_size, void* d_ws, size_t ws_size,
                              hipStream_t stream) {
    const float* emb   = (const float*)d_in[0];
    const int*   items = (const int*)d_in[1];
    const float* A     = (const float*)d_in[2];
    const float* D     = (const float*)d_in[3];
    float* out = (float*)d_out;

    uchar* base = (uchar*)d_ws;
    int*   flag = (int*)base;
    uchar* rtab = base + 64;
    uchar* ctab = base + 320;
    float*  Ef  = (float*)(base + 1024);
    __bf16* ETp = (__bf16*)(Ef + NB);
    __bf16* TTp = ETp + NB;
    float*  Tp  = (float*)(TTp + NB);
    float*  RpX = Tp + 4 * NB;

    probe_kernel<<<1, 64, 0, stream>>>(flag, rtab, ctab);
    gather_sum_kernel<<<BATCH / 2, 256, 0, stream>>>(emb, items, Ef, ETp);

    // Phase 1: T = A @ E
    gemm_mfma_kernel<1><<<dim3(BATCH / 16, 4), 256, 0, stream>>>(A, ETp, flag, rtab, ctab, Tp, RpX);
    gemm_fp32_kernel<1><<<dim3(BATCH / 32, 4), 256, 0, stream>>>(A, Ef, flag, Tp, RpX);
    reduce4_kernel<<<512, 256, 0, stream>>>(Tp, TTp);

    // Phase 2: R = D @ T, then row-normalize
    gemm_mfma_kernel<2><<<dim3(BATCH / 16, 4), 256, 0, stream>>>(D, TTp, flag, rtab, ctab, Tp, RpX);
    gemm_fp32_kernel<2><<<dim3(BATCH / 32, 4), 256, 0, stream>>>(D, Tp, flag, Tp, RpX);
    reduce_norm_kernel<<<BATCH, 128, 0, stream>>>(Tp, RpX, out);
}